// Round 8
// baseline (15632.887 us; speedup 1.0000x reference)
//
#include <hip/hip_runtime.h>
#include <cstdint>
#include <math.h>

typedef unsigned int u32;
typedef unsigned long long u64;
typedef double d4 __attribute__((ext_vector_type(4)));

#define TF_PARTITIONABLE 1

#define NU 6144
#define NB 32
#define NTOT (NU * NB)      // 196608
#define NWORD 96            // u64 words per sample row
#define NCH 12              // split-K chunks per GEMM
#define CHK 512             // k per chunk (NCH*CHK = NU)
#define NT_TILES 16         // CHK / 32
#define HALF_BIG 98304u
#define HALF_SMALL 16u

struct Key { u32 a, b; };
struct UVec { float u[NB]; };

// ---------------- threefry2x32 (20 rounds), matches jax._src.prng ----------------
__host__ __device__ __forceinline__ void tf2x32(u32 k0, u32 k1, u32 x0, u32 x1, u32& o0, u32& o1) {
  const u32 k2 = k0 ^ k1 ^ 0x1BD11BDAu;
#define TFR(r) { x0 += x1; x1 = (x1 << r) | (x1 >> (32 - r)); x1 ^= x0; }
  x0 += k0; x1 += k1;
  TFR(13) TFR(15) TFR(26) TFR(6)  x0 += k1; x1 += k2 + 1u;
  TFR(17) TFR(29) TFR(16) TFR(24) x0 += k2; x1 += k0 + 2u;
  TFR(13) TFR(15) TFR(26) TFR(6)  x0 += k0; x1 += k1 + 3u;
  TFR(17) TFR(29) TFR(16) TFR(24) x0 += k1; x1 += k2 + 4u;
  TFR(13) TFR(15) TFR(26) TFR(6)  x0 += k2; x1 += k0 + 5u;
#undef TFR
  o0 = x0; o1 = x1;
}

__host__ __device__ __forceinline__ u32 rbits(u32 k0, u32 k1, u32 t, u32 half) {
#if TF_PARTITIONABLE
  (void)half;
  u32 a, b; tf2x32(k0, k1, 0u, t, a, b); return a ^ b;
#else
  u32 a, b;
  if (t < half) { tf2x32(k0, k1, t, half + t, a, b); return a; }
  tf2x32(k0, k1, t - half, t, a, b); return b;
#endif
}

__host__ __device__ __forceinline__ float u01f(u32 bits) {
  union { u32 u; float f; } c; c.u = (bits >> 9) | 0x3f800000u;
  return c.f - 1.0f;
}

// ---------------- MFMA f64 layout self-calibration ----------------
__device__ __forceinline__ double pav(int probe, int l) {
  return probe ? (double)(((l * 13 + 5) & 63) + 1) : (double)(l + 1);
}
__device__ __forceinline__ double pbv(int probe, int l) {
  return probe ? (double)(((l * 11 + 2) & 63) + 1) : (double)(((l * 7 + 3) & 63) + 1);
}

// tbl[lane*16 + {0..8}] = mA,kA,nB,kB,bD0,bDs,jD0,jDs,ok
__global__ __launch_bounds__(64) void k_calib(int* __restrict__ tbl) {
  int L = threadIdx.x;
  d4 z = {0.0, 0.0, 0.0, 0.0};
  d4 o0 = __builtin_amdgcn_mfma_f64_16x16x4f64(pav(0, L), pbv(0, L), z, 0, 0, 0);
  d4 o1 = __builtin_amdgcn_mfma_f64_16x16x4f64(pav(1, L), pbv(1, L), z, 0, 0, 0);
  int q = L >> 4, m16 = L & 15;
  int best = -1;
  for (int combo = 0; combo < 16; ++combo) {
    int fa = combo & 1, fb = (combo >> 1) & 1, fd = combo >> 2;
    int ok = 1;
    for (int probe = 0; probe < 2; ++probe) {
#pragma unroll
      for (int r = 0; r < 4; ++r) {
        int i, j;
        if (fd == 0)      { j = m16; i = 4 * q + r; }
        else if (fd == 1) { j = m16; i = q + 4 * r; }
        else if (fd == 2) { i = m16; j = 4 * q + r; }
        else              { i = m16; j = q + 4 * r; }
        double pred = 0.0;
#pragma unroll
        for (int k = 0; k < 4; ++k) {
          int la = fa ? (i * 4 + k) : (k * 16 + i);
          int lb = fb ? (j * 4 + k) : (k * 16 + j);
          pred += pav(probe, la) * pbv(probe, lb);
        }
        double obs = probe ? (r == 0 ? o1[0] : r == 1 ? o1[1] : r == 2 ? o1[2] : o1[3])
                           : (r == 0 ? o0[0] : r == 1 ? o0[1] : r == 2 ? o0[2] : o0[3]);
        if (pred != obs) ok = 0;
      }
    }
    if (__all(ok) && best < 0) best = combo;
  }
  int mA = 0, kA = 0, nB = 0, kB = 0, b0_ = 0, bs = 0, j0 = 0, js = 0, okf = 0;
  if (best >= 0) {
    int fa = best & 1, fb = (best >> 1) & 1, fd = best >> 2;
    if (fa) { mA = L >> 2; kA = L & 3; } else { mA = m16; kA = q; }
    if (fb) { nB = L >> 2; kB = L & 3; } else { nB = m16; kB = q; }
    if (fd == 0)      { j0 = m16; js = 0; b0_ = 4 * q; bs = 1; }
    else if (fd == 1) { j0 = m16; js = 0; b0_ = q; bs = 4; }
    else if (fd == 2) { b0_ = m16; bs = 0; j0 = 4 * q; js = 1; }
    else              { b0_ = m16; bs = 0; j0 = q; js = 4; }
    okf = 1;
  }
  int* p = tbl + L * 16;
  p[0] = mA; p[1] = kA; p[2] = nB; p[3] = kB;
  p[4] = b0_; p[5] = bs; p[6] = j0; p[7] = js; p[8] = okf;
}

// ---------------- control kernels ----------------
__global__ void k_init(u32* __restrict__ flag, u32* __restrict__ chg) { *flag = 0u; *chg = 0u; }

__global__ void k_conv(u32* __restrict__ flag, u32* __restrict__ chg) {
  if (*flag == 0u && *chg == 0u) *flag = 1u;   // T=0 fixed point reached -> skip rest of LS
  *chg = 0u;
}

__global__ void k_allconv(const u32* __restrict__ conv, u32* __restrict__ skipc) {
  if (*skipc) return;
  u32 all = 1u;
  for (int b = 0; b < NB; ++b) all &= conv[b];
  if (all) *skipc = 1u;
}

// ---------------- state init ----------------
__global__ __launch_bounds__(256) void k_pos_v(const float* __restrict__ vin,
                                               double* __restrict__ xf, u64* __restrict__ pk) {
  int tid = blockIdx.x * 256 + threadIdx.x;          // 24576 = 32*768
  int b = tid / 768, p = tid % 768;
  float x = vin[tid];
  int q = (int)floorf(x * 256.0f);
  q = q < 0 ? 0 : (q > 255 ? 255 : q);
  ((unsigned char*)pk)[b * 768 + p] = (unsigned char)q;   // byte == 8 LSB-first bits
  int ubase = p * 8;
#pragma unroll
  for (int bit = 0; bit < 8; ++bit)
    xf[(size_t)(ubase + bit) * NB + b] = (double)((q >> bit) & 1);
}

__global__ __launch_bounds__(256) void k_bern(u32 k0, u32 k1,
                                              double* __restrict__ xf, u64* __restrict__ pk,
                                              const u32* __restrict__ skip) {
  if (skip && *skip) return;
  int tid = blockIdx.x * 256 + threadIdx.x;          // 196608
  int b = tid / NU, j = tid % NU;
  float u = u01f(rbits(k0, k1, (u32)tid, HALF_BIG));
  bool s = u < 0.5f;
  u64 m = __ballot(s);
  if ((threadIdx.x & 63) == 0) pk[tid >> 6] = m;
  xf[(size_t)j * NB + b] = s ? 1.0 : 0.0;
}

// ---------------- sampling ----------------
__device__ __forceinline__ bool samp_dec(float f, int t1, u32 k0, u32 k1, u32 tid) {
  if (t1) {
    double u = (double)u01f(rbits(k0, k1, tid, HALF_BIG));
    return u < 1.0 / (1.0 + exp(-(double)f));
  }
  return f >= 0.0f;
}

__global__ __launch_bounds__(256) void k_samp(const float* __restrict__ fE, const float* __restrict__ fO,
                                              u32 even, int t1, u32 k0, u32 k1,
                                              double* __restrict__ xf, u64* __restrict__ pk,
                                              const u32* __restrict__ skip, u32* __restrict__ chg) {
  if (skip && *skip) return;
  int tid = blockIdx.x * 256 + threadIdx.x;
  int b = tid / NU, j = tid % NU;
  float f = ((even >> b) & 1u) ? fE[tid] : fO[tid];
  bool s = samp_dec(f, t1, k0, k1, (u32)tid);
  u64 m = __ballot(s);
  if ((threadIdx.x & 63) == 0) {
    int widx = tid >> 6;
    if (chg) { u64 old = pk[widx]; if (old != m) *chg = 1u; }  // benign race
    pk[widx] = m;
  }
  xf[(size_t)j * NB + b] = s ? 1.0 : 0.0;
}

// ---------------- GEMM kernels: W-only LDS dbuf MFMA, x from L2; VALU fallback ----------------
// out[b][j] = sum_k x[k][b] * W[k][j]  (x @ W)
__global__ __launch_bounds__(256) void k_gemm_n(const float* __restrict__ W, const double* __restrict__ xf,
                                                double* __restrict__ part, const u32* __restrict__ skip,
                                                const int* __restrict__ tbl) {
  if (skip && *skip) return;
  __shared__ double smem_d[2560];              // 20480 B (W tiles / fallback red)
  int jt = blockIdx.x % 96, c = blockIdx.x / 96;     // grid 96*NCH
  int wid = threadIdx.x >> 6, lane = threadIdx.x & 63;
  int kbase = c * CHK;
  int jn0 = jt * 64;
  const int* tp = tbl + lane * 16;
  int okf = tp[8];
  if (okf) {
    float* lw = (float*)smem_d;                // [2][32][80]
    int mA = tp[0], kA = tp[1], nB = tp[2], kB = tp[3];
    int bD0 = tp[4], bDs = tp[5], jD0 = tp[6], jDs = tp[7];
    int t256 = threadIdx.x;
    d4 acc0 = {0.0, 0.0, 0.0, 0.0};
    d4 acc1 = {0.0, 0.0, 0.0, 0.0};
#pragma unroll
    for (int r = 0; r < 2; ++r) {
      int idx = r * 256 + t256, kk = idx >> 4, qq = idx & 15;
      float4 w4 = *(const float4*)(W + (size_t)(kbase + kk) * NU + jn0 + 4 * qq);
      float* d = &lw[kk * 80 + 4 * qq];
      d[0] = w4.x; d[1] = w4.y; d[2] = w4.z; d[3] = w4.w;
    }
    __syncthreads();
    const double* xa = xf + (size_t)(kbase + kA) * NB + mA;
    int buf = 0;
    for (int t = 0; t < NT_TILES; ++t) {
      float4 w0p, w1p;
      bool pf = (t + 1) < NT_TILES;
      if (pf) {
        int k0n = kbase + (t + 1) * 32;
        { int idx = t256,       kk = idx >> 4, qq = idx & 15;
          w0p = *(const float4*)(W + (size_t)(k0n + kk) * NU + jn0 + 4 * qq); }
        { int idx = 256 + t256, kk = idx >> 4, qq = idx & 15;
          w1p = *(const float4*)(W + (size_t)(k0n + kk) * NU + jn0 + 4 * qq); }
      }
      const float* lwp = &lw[(buf * 32 + kB) * 80 + wid * 16 + nB];
      const double* xt = xa + (size_t)t * 32 * NB;
#pragma unroll
      for (int u = 0; u < 8; ++u) {
        double a0 = xt[u * 4 * NB];
        double a1 = xt[u * 4 * NB + 16];
        double wv = (double)lwp[320 * u];
        acc0 = __builtin_amdgcn_mfma_f64_16x16x4f64(a0, wv, acc0, 0, 0, 0);
        acc1 = __builtin_amdgcn_mfma_f64_16x16x4f64(a1, wv, acc1, 0, 0, 0);
      }
      if (pf) {
        int nb = buf ^ 1;
        { int idx = t256,       kk = idx >> 4, qq = idx & 15;
          float* d = &lw[(nb * 32 + kk) * 80 + 4 * qq];
          d[0] = w0p.x; d[1] = w0p.y; d[2] = w0p.z; d[3] = w0p.w; }
        { int idx = 256 + t256, kk = idx >> 4, qq = idx & 15;
          float* d = &lw[(nb * 32 + kk) * 80 + 4 * qq];
          d[0] = w1p.x; d[1] = w1p.y; d[2] = w1p.z; d[3] = w1p.w; }
      }
      __syncthreads();
      buf ^= 1;
    }
    int jn = jn0 + wid * 16;
    double* pp = part + (size_t)c * NTOT + jn;
#pragma unroll
    for (int r = 0; r < 4; ++r) {
      int bi = bD0 + bDs * r, jj = jD0 + jDs * r;
      pp[(size_t)bi * NU + jj] = acc0[r];
      pp[(size_t)(bi + 16) * NU + jj] = acc1[r];
    }
  } else {
    // VALU fallback: wave wid sums k in [kbase + wid*128, +128)
    double* red = smem_d;
    int j = jn0 + lane;
    int i0 = kbase + wid * 128;
    const float* wp = W + (size_t)i0 * NU + j;
    const double* xp = xf + (size_t)i0 * NB;
    double acc[32];
#pragma unroll
    for (int b = 0; b < 32; ++b) acc[b] = 0.0;
    for (int i = 0; i < 128; ++i) {
      double w = (double)wp[(size_t)i * NU];
      const double* xq = xp + (size_t)i * NB;
#pragma unroll
      for (int b = 0; b < 32; ++b) acc[b] = fma(xq[b], w, acc[b]);
    }
    for (int w = 1; w < 4; ++w) {
      if (wid == w) {
#pragma unroll
        for (int b = 0; b < 32; ++b) red[b * 64 + lane] = acc[b];
      }
      __syncthreads();
      if (wid == 0) {
#pragma unroll
        for (int b = 0; b < 32; ++b) acc[b] += red[b * 64 + lane];
      }
      __syncthreads();
    }
    if (wid == 0) {
      double* pp = part + (size_t)c * NTOT + j;
#pragma unroll
      for (int b = 0; b < 32; ++b) pp[(size_t)b * NU] = acc[b];
    }
  }
}

// out[b][j] = sum_k x[k][b] * W[j][k]  (x @ W.T); W tile staged natural [j][k], transposed at read
__global__ __launch_bounds__(256) void k_gemm_t(const float* __restrict__ W, const double* __restrict__ xf,
                                                double* __restrict__ part, const u32* __restrict__ skip,
                                                const int* __restrict__ tbl) {
  if (skip && *skip) return;
  __shared__ double smem_d[2176];              // 17408 B (W tiles / fallback lwf+red alias)
  int jt = blockIdx.x % 96, c = blockIdx.x / 96;
  int wid = threadIdx.x >> 6, lane = threadIdx.x & 63;
  int kbase = c * CHK;
  int jn0 = jt * 64;
  const int* tp = tbl + lane * 16;
  int okf = tp[8];
  if (okf) {
    float* lw = (float*)smem_d;                // [2][64][34], [j][k]
    int mA = tp[0], kA = tp[1], nB = tp[2], kB = tp[3];
    int bD0 = tp[4], bDs = tp[5], jD0 = tp[6], jDs = tp[7];
    int t256 = threadIdx.x;
    d4 acc0 = {0.0, 0.0, 0.0, 0.0};
    d4 acc1 = {0.0, 0.0, 0.0, 0.0};
#pragma unroll
    for (int r = 0; r < 2; ++r) {
      int idx = r * 256 + t256, jj = idx >> 3, kq = idx & 7;
      float4 w4 = *(const float4*)(W + (size_t)(jn0 + jj) * NU + kbase + 4 * kq);
      float* d = &lw[jj * 34 + 4 * kq];
      d[0] = w4.x; d[1] = w4.y; d[2] = w4.z; d[3] = w4.w;
    }
    __syncthreads();
    const double* xa = xf + (size_t)(kbase + kA) * NB + mA;
    int buf = 0;
    for (int t = 0; t < NT_TILES; ++t) {
      float4 w0p, w1p;
      bool pf = (t + 1) < NT_TILES;
      if (pf) {
        int k0n = kbase + (t + 1) * 32;
        { int idx = t256,       jj = idx >> 3, kq = idx & 7;
          w0p = *(const float4*)(W + (size_t)(jn0 + jj) * NU + k0n + 4 * kq); }
        { int idx = 256 + t256, jj = idx >> 3, kq = idx & 7;
          w1p = *(const float4*)(W + (size_t)(jn0 + jj) * NU + k0n + 4 * kq); }
      }
      const float* lwp = &lw[(buf * 64 + wid * 16 + nB) * 34 + kB];
      const double* xt = xa + (size_t)t * 32 * NB;
#pragma unroll
      for (int u = 0; u < 8; ++u) {
        double a0 = xt[u * 4 * NB];
        double a1 = xt[u * 4 * NB + 16];
        double wv = (double)lwp[4 * u];
        acc0 = __builtin_amdgcn_mfma_f64_16x16x4f64(a0, wv, acc0, 0, 0, 0);
        acc1 = __builtin_amdgcn_mfma_f64_16x16x4f64(a1, wv, acc1, 0, 0, 0);
      }
      if (pf) {
        int nb = buf ^ 1;
        { int idx = t256,       jj = idx >> 3, kq = idx & 7;
          float* d = &lw[(nb * 64 + jj) * 34 + 4 * kq];
          d[0] = w0p.x; d[1] = w0p.y; d[2] = w0p.z; d[3] = w0p.w; }
        { int idx = 256 + t256, jj = idx >> 3, kq = idx & 7;
          float* d = &lw[(nb * 64 + jj) * 34 + 4 * kq];
          d[0] = w1p.x; d[1] = w1p.y; d[2] = w1p.z; d[3] = w1p.w; }
      }
      __syncthreads();
      buf ^= 1;
    }
    int jn = jn0 + wid * 16;
    double* pp = part + (size_t)c * NTOT + jn;
#pragma unroll
    for (int r = 0; r < 4; ++r) {
      int bi = bD0 + bDs * r, jj = jD0 + jDs * r;
      pp[(size_t)bi * NU + jj] = acc0[r];
      pp[(size_t)(bi + 16) * NU + jj] = acc1[r];
    }
  } else {
    // VALU fallback with LDS-transposed W tiles (NT_TILES stages of 32 k); red aliases lwf (sequential)
    float* lwf = (float*)smem_d;               // 32x65 f32
    double* red = smem_d;                      // used strictly after last lwf read
    int qf = threadIdx.x & 7, af = threadIdx.x >> 3;
    double acc[32];
#pragma unroll
    for (int b = 0; b < 32; ++b) acc[b] = 0.0;
    for (int s = 0; s < NT_TILES; ++s) {
      int ib = kbase + s * 32;
#pragma unroll
      for (int pass = 0; pass < 2; ++pass) {
        int r = pass * 32 + af;
        float4 w4 = *(const float4*)(W + (size_t)(jn0 + r) * NU + ib + qf * 4);
        lwf[(qf * 4 + 0) * 65 + r] = w4.x;
        lwf[(qf * 4 + 1) * 65 + r] = w4.y;
        lwf[(qf * 4 + 2) * 65 + r] = w4.z;
        lwf[(qf * 4 + 3) * 65 + r] = w4.w;
      }
      __syncthreads();
      int iw = wid * 8;
      for (int ii = 0; ii < 8; ++ii) {
        double w = (double)lwf[(iw + ii) * 65 + lane];
        const double* xq = xf + (size_t)(ib + iw + ii) * NB;
#pragma unroll
        for (int b = 0; b < 32; ++b) acc[b] = fma(xq[b], w, acc[b]);
      }
      __syncthreads();
    }
    for (int w = 1; w < 4; ++w) {
      if (wid == w) {
#pragma unroll
        for (int b = 0; b < 32; ++b) red[b * 64 + lane] = acc[b];
      }
      __syncthreads();
      if (wid == 0) {
#pragma unroll
        for (int b = 0; b < 32; ++b) acc[b] += red[b * 64 + lane];
      }
      __syncthreads();
    }
    if (wid == 0) {
      double* pp = part + (size_t)c * NTOT + jn0 + lane;
#pragma unroll
      for (int b = 0; b < 32; ++b) pp[(size_t)b * NU] = acc[b];
    }
  }
}

// ---------------- reduce (+ optional fused sample) ----------------
__global__ __launch_bounds__(256) void k_reduce(const double* __restrict__ part, const float* __restrict__ bias,
                                                const float* __restrict__ src, float* __restrict__ out,
                                                const u32* __restrict__ skip) {
  if (skip && *skip) return;
  int tid = blockIdx.x * 256 + threadIdx.x;
  int j = tid % NU;
  double s = src ? (double)src[tid] : 0.0;
  if (bias) s += (double)bias[j];
#pragma unroll
  for (int c = 0; c < NCH; ++c) s += part[(size_t)c * NTOT + tid];
  out[tid] = (float)s;
}

// reduce -> F; sample into xf/pk for batch rows in wmask; optional chg detection
__global__ __launch_bounds__(256) void k_redsamp(const double* __restrict__ part, const float* __restrict__ bias,
                                                 const float* __restrict__ src, float* __restrict__ out,
                                                 int t1, u32 k0, u32 k1,
                                                 double* __restrict__ xf, u64* __restrict__ pk,
                                                 const u32* __restrict__ skip, u32 wmask,
                                                 u32* __restrict__ chg) {
  if (skip && *skip) return;
  int tid = blockIdx.x * 256 + threadIdx.x;
  int j = tid % NU, b = tid / NU;
  double s = src ? (double)src[tid] : 0.0;
  if (bias) s += (double)bias[j];
#pragma unroll
  for (int c = 0; c < NCH; ++c) s += part[(size_t)c * NTOT + tid];
  float f = (float)s;
  out[tid] = f;
  bool wr = (wmask >> b) & 1u;
  bool smp = samp_dec(f, t1, k0, k1, (u32)tid);
  u64 m = __ballot(smp);
  if (((threadIdx.x & 63) == 0) && wr) {
    int widx = tid >> 6;
    if (chg) { u64 old = pk[widx]; if (old != m) *chg = 1u; }
    pk[widx] = m;
  }
  if (wr) xf[(size_t)j * NB + b] = smp ? 1.0 : 0.0;
}

// ---------------- energy / accept / merge ----------------
__global__ __launch_bounds__(256) void k_energy(const u64* __restrict__ pkv, const u64* __restrict__ pkh0,
                                                const u64* __restrict__ pkh1, const float* __restrict__ f1,
                                                const float* __restrict__ f2, const float* __restrict__ b0,
                                                float* __restrict__ eout, const u32* __restrict__ skip) {
  if (skip && *skip) return;
  __shared__ double red[256];
  int b = blockIdx.x, t = threadIdx.x;
  double s = 0.0;
  for (int j = t; j < NU; j += 256) {
    int w = j >> 6, bit = j & 63;
    if ((pkv [b * NWORD + w] >> bit) & 1ull) s += (double)b0[j];
    if ((pkh0[b * NWORD + w] >> bit) & 1ull) s += (double)f1[(size_t)b * NU + j];
    if ((pkh1[b * NWORD + w] >> bit) & 1ull) s += (double)f2[(size_t)b * NU + j];
  }
  red[t] = s; __syncthreads();
  for (int off = 128; off > 0; off >>= 1) { if (t < off) red[t] += red[t + off]; __syncthreads(); }
  if (t == 0) eout[b] = (float)(-red[0]);
}

__global__ __launch_bounds__(64) void k_accept(float* __restrict__ ecur, const float* __restrict__ eprop,
                                               float* __restrict__ erun, u32* __restrict__ conv,
                                               u32* __restrict__ accf,
                                               const u64* __restrict__ pv, const u64* __restrict__ pcv,
                                               const u64* __restrict__ ph0, const u64* __restrict__ pch0,
                                               const u64* __restrict__ ph1, const u64* __restrict__ pch1,
                                               UVec uv, int first, const u32* __restrict__ skip) {
  if (skip && *skip) return;
  int b = blockIdx.x, t = threadIdx.x;
  u64 diff = 0ull;
  for (int w = t; w < NWORD; w += 64) {
    size_t o = (size_t)b * NWORD + w;
    if (pv) diff |= pv[o] ^ pcv[o];
    diff |= ph0[o] ^ pch0[o];
    diff |= ph1[o] ^ pch1[o];
  }
  int neq = __any(diff != 0ull);
  if (t == 0) {
    float ec = ecur[b], ep = eprop[b];
    bool acc = (double)uv.u[b] < exp(fmin((double)ec - (double)ep, 0.0));
    bool m = first ? true : (conv[b] == 0u);
    bool upd = m && acc;
    if (first) erun[b] = acc ? ep : ec;
    else if (upd) erun[b] += (ep - ec);
    if (upd) ecur[b] = ep;
    u32 c2 = acc ? (neq ? 0u : 1u) : 1u;
    conv[b] = first ? c2 : (conv[b] | c2);
    accf[b] = upd ? 1u : 0u;
  }
}

__global__ __launch_bounds__(256) void k_merge_xf(const u32* __restrict__ accf,
                                                  const u64* __restrict__ pa, u64* __restrict__ ca,
                                                  const u64* __restrict__ pb, u64* __restrict__ cb,
                                                  const u64* __restrict__ pc, u64* __restrict__ cc,
                                                  const u32* __restrict__ skip) {
  if (skip && *skip) return;
  int tid = blockIdx.x * 256 + threadIdx.x;          // over NTOT (f64 copy as u64)
  int b = tid & 31;                                  // xf layout [unit][b]
  if (accf[b]) {
    ca[tid] = pa[tid];
    cb[tid] = pb[tid];
    if (pc) cc[tid] = pc[tid];
  }
}

__global__ __launch_bounds__(256) void k_merge_pk(const u32* __restrict__ accf,
                                                  const u64* __restrict__ pa, u64* __restrict__ ca,
                                                  const u64* __restrict__ pb, u64* __restrict__ cb,
                                                  const u64* __restrict__ pc, u64* __restrict__ cc,
                                                  const u32* __restrict__ skip) {
  if (skip && *skip) return;
  int w = blockIdx.x * 256 + threadIdx.x;
  if (w >= NB * NWORD) return;
  int b = w / NWORD;
  if (accf[b]) {
    ca[w] = pa[w];
    cb[w] = pb[w];
    if (pc) cc[w] = pc[w];
  }
}

__global__ void k_final(const float* __restrict__ ep, const float* __restrict__ en, float* __restrict__ out) {
  int b = threadIdx.x;
  if (b < NB) out[b] = ep[b] - en[b];
}

// ---------------- host-side key derivation ----------------
static void split_keys(Key k, int n, Key* out) {
#if TF_PARTITIONABLE
  for (int i = 0; i < n; ++i) { u32 a, b; tf2x32(k.a, k.b, 0u, (u32)i, a, b); out[i].a = a; out[i].b = b; }
#else
  u32 flat[64];
  for (int i = 0; i < n; ++i) { u32 a, b; tf2x32(k.a, k.b, (u32)i, (u32)(n + i), a, b); flat[i] = a; flat[n + i] = b; }
  for (int i = 0; i < n; ++i) { out[i].a = flat[2 * i]; out[i].b = flat[2 * i + 1]; }
#endif
}
static u32 mask32(Key k) {
  u32 m = 0;
  for (int b = 0; b < NB; ++b)
    if (u01f(rbits(k.a, k.b, (u32)b, HALF_SMALL)) < 0.5f) m |= (1u << b);
  return m;
}

extern "C" void kernel_launch(void* const* d_in, const int* in_sizes, int n_in,
                              void* d_out, int out_size, void* d_ws, size_t ws_size,
                              hipStream_t stream) {
  const float* vin = (const float*)d_in[0];
  const float* W0  = (const float*)d_in[1];
  const float* W1  = (const float*)d_in[2];
  const float* b0  = (const float*)d_in[3];
  const float* b1  = (const float*)d_in[4];
  const float* b2  = (const float*)d_in[5];
  float* outp = (float*)d_out;

  // ---- workspace layout (~38.8 MB; round-2 proved >=40.3 available) ----
  char* ws = (char*)d_ws;
  size_t off = 0;
  auto alloc = [&](size_t bytes) -> void* {
    void* p = ws + off; off += (bytes + 255) & ~(size_t)255; return p;
  };
  enum { SV = 0, SH0, SH1, SVE, SH1E, SH0O, SVP, SH0P, SH1P, NS };
  enum { IV = 0, IA, IB, IC, ID, IE, IF2, NF };   // coupling reuses IC/ID as scratch
  double* XF[NS]; u64* PK[NS]; float* F[NF];
  for (int s = 0; s < NS; ++s) XF[s] = (double*)alloc((size_t)NTOT * 8);
  for (int f = 0; f < NF; ++f) F[f]  = (float*)alloc((size_t)NTOT * 4);
  double* PART = (double*)alloc((size_t)NCH * NTOT * 8);
  for (int s = 0; s < NS; ++s) PK[s] = (u64*)alloc((size_t)NB * NWORD * 8);
  int*   TBL    = (int*)alloc(64 * 16 * 4);
  float* E_CUR  = (float*)alloc(256);
  float* E_PROP = (float*)alloc(256);
  float* E_POS  = (float*)alloc(256);
  float* E_NEG  = (float*)alloc(256);
  u32*   ACC    = (u32*)alloc(256);
  u32*   CONV   = (u32*)alloc(256);
  u32*   FLAG   = (u32*)alloc(256);
  u32*   CHG    = (u32*)alloc(256);
  u32*   SKIPC  = (u32*)alloc(256);
  u32*   DUMMY  = (u32*)alloc(256);
  if (off > ws_size) return;

  // ---- host RNG: full key tree from jax.random.key(42) ----
  Key root{0u, 42u};
  Key ks[13]; split_keys(root, 13, ks);
  const Key KZ{0u, 0u};

  // ---- MFMA layout calibration (deterministic, graph-safe) ----
  k_calib<<<dim3(1), dim3(64), 0, stream>>>(TBL);

  // ---- launch helpers ----
  auto GEMM_T = [&](const float* Wm, int xs, const u32* skip) {
    k_gemm_t<<<dim3(96 * NCH), dim3(256), 0, stream>>>(Wm, XF[xs], PART, skip, TBL);
  };
  auto GEMM_N = [&](const float* Wm, int xs, const u32* skip) {
    k_gemm_n<<<dim3(96 * NCH), dim3(256), 0, stream>>>(Wm, XF[xs], PART, skip, TBL);
  };
  auto RED = [&](const float* bias, const float* src, float* dst, const u32* skip) {
    k_reduce<<<dim3(768), dim3(256), 0, stream>>>(PART, bias, src, dst, skip);
  };
  auto REDS = [&](const float* bias, const float* src, float* dst, int t1, Key k, int sdst,
                  const u32* skip, u32 wm, u32* chg) {
    k_redsamp<<<dim3(768), dim3(256), 0, stream>>>(PART, bias, src, dst, t1, k.a, k.b,
                                                   XF[sdst], PK[sdst], skip, wm, chg);
  };
  auto GT = [&](const float* Wm, int xs, const float* bias, const float* src, float* dst, const u32* skip) {
    GEMM_T(Wm, xs, skip); RED(bias, src, dst, skip);
  };
  auto GN = [&](const float* Wm, int xs, const float* bias, const float* src, float* dst, const u32* skip) {
    GEMM_N(Wm, xs, skip); RED(bias, src, dst, skip);
  };
  auto GTS = [&](const float* Wm, int xs, const float* bias, const float* src, float* dst,
                 int t1, Key k, int sdst, const u32* skip) {
    GEMM_T(Wm, xs, skip); REDS(bias, src, dst, t1, k, sdst, skip, ~0u, nullptr);
  };
  auto GNS = [&](const float* Wm, int xs, const float* bias, const float* src, float* dst,
                 int t1, Key k, int sdst, const u32* skip) {
    GEMM_N(Wm, xs, skip); REDS(bias, src, dst, t1, k, sdst, skip, ~0u, nullptr);
  };
  auto SAMP = [&](const float* fE, const float* fO, u32 even, int t1, Key k, int dst,
                  const u32* skip, u32* chg) {
    k_samp<<<dim3(768), dim3(256), 0, stream>>>(fE, fO, even, t1, k.a, k.b, XF[dst], PK[dst], skip, chg);
  };
  auto BERN = [&](Key k, int dst, const u32* skip) {
    k_bern<<<dim3(768), dim3(256), 0, stream>>>(k.a, k.b, XF[dst], PK[dst], skip);
  };
  auto ENERGY = [&](int sv, int sh0, int sh1, const float* f1, const float* f2, float* eo, const u32* skip) {
    k_energy<<<dim3(32), dim3(256), 0, stream>>>(PK[sv], PK[sh0], PK[sh1], f1, f2, b0, eo, skip);
  };

  // ===== staggered T=0 local search (round-7 proven) =====
  auto ls_fixv = [&](u32 evm) {
    auto X = [&](u32 wm) {
      GEMM_T(W1, SH0, FLAG);
      REDS(b2, nullptr, F[IA], 0, KZ, SH1, FLAG, wm, CHG);
    };
    auto Y = [&]() {
      GEMM_N(W1, SH1, FLAG);
      REDS(nullptr, F[IV], F[IC], 0, KZ, SH0, FLAG, ~0u, CHG);
    };
    k_init<<<dim3(1), dim3(1), 0, stream>>>(FLAG, CHG);
    X(evm);
    for (int i = 0; i < 31; ++i) {
      Y(); X(~0u);
      k_conv<<<dim3(1), dim3(1), 0, stream>>>(FLAG, CHG);
    }
    Y(); X(~evm);
  };
  auto ls_free = [&](u32 evm) {
    auto X = [&](u32 wm) {
      GEMM_N(W0, SH0, FLAG);
      REDS(b0, nullptr, F[IE], 0, KZ, SV, FLAG, wm, CHG);
      GEMM_T(W1, SH0, FLAG);
      REDS(b2, nullptr, F[IA], 0, KZ, SH1, FLAG, wm, CHG);
    };
    auto Y = [&]() {
      GT(W0, SV, b1, nullptr, F[IC], FLAG);
      GEMM_N(W1, SH1, FLAG);
      REDS(nullptr, F[IC], F[IC], 0, KZ, SH0, FLAG, ~0u, CHG);
    };
    k_init<<<dim3(1), dim3(1), 0, stream>>>(FLAG, CHG);
    X(evm);
    for (int i = 0; i < 31; ++i) {
      Y(); X(~0u);
      k_conv<<<dim3(1), dim3(1), 0, stream>>>(FLAG, CHG);
    }
    Y(); X(~evm);
  };

  // ===== T=1 gibbs steps =====
  auto gibbs_fixv = [&](u32 even, Key kh0, Key kh1) {
    GTS(W1, SH0, b2, nullptr, F[IA], 1, kh1, SH1E, nullptr);     // f_h1e ; h1_e
    GN(W1, SH1E, nullptr, F[IV], F[IB], nullptr);                // f_h0e = fv + h1_e@W1
    GNS(W1, SH1, nullptr, F[IV], F[IC], 1, kh0, SH0O, nullptr);  // f_h0o ; h0_o
    GT(W1, SH0O, b2, nullptr, F[ID], nullptr);                   // f_h1o
    SAMP(F[IB], F[IC], even, 1, kh0, SH0, nullptr, nullptr);     // h0 merge
    SAMP(F[IA], F[ID], even, 1, kh1, SH1, nullptr, nullptr);     // h1 merge
  };
  auto gibbs_free = [&](u32 even, Key kv, Key kh0, Key kh1) {
    GNS(W0, SH0, b0, nullptr, F[IE], 1, kv, SVE, nullptr);       // f_ve ; v_e
    GTS(W1, SH0, b2, nullptr, F[IA], 1, kh1, SH1E, nullptr);     // f_h1e ; h1_e
    GT(W0, SVE, b1, nullptr, F[IB], nullptr);                    // f_h0e = v_e@W0.T + b1
    GN(W1, SH1E, nullptr, F[IB], F[IB], nullptr);                //        + h1_e@W1
    GT(W0, SV, b1, nullptr, F[IC], nullptr);                     // f_h0o = v@W0.T + b1
    GNS(W1, SH1, nullptr, F[IC], F[IC], 1, kh0, SH0O, nullptr);  //        + h1@W1 ; h0_o
    GN(W0, SH0O, b0, nullptr, F[IF2], nullptr);                  // f_vo
    GT(W1, SH0O, b2, nullptr, F[ID], nullptr);                   // f_h1o
    SAMP(F[IE], F[IF2], even, 1, kv, SV, nullptr, nullptr);      // v merge
    SAMP(F[IB], F[IC], even, 1, kh0, SH0, nullptr, nullptr);     // h0 merge
    SAMP(F[IA], F[ID], even, 1, kh1, SH1, nullptr, nullptr);     // h1 merge
  };

  // ===== coupling; E_CUR holds energy(cur); fixv uses F[IV]=fv; IC/ID free scratch here =====
  auto coupling = [&](bool fixv, Key ck, float* erun) {
    Key top[2]; split_keys(ck, 2, top);
    Key cks[17]; cks[0] = top[0];
    { Key rest[16]; split_keys(top[1], 16, rest); for (int i = 0; i < 16; ++i) cks[i + 1] = rest[i]; }
    k_init<<<dim3(1), dim3(1), 0, stream>>>(SKIPC, DUMMY);
    for (int it = 0; it < 17; ++it) {
      const u32* sk = (it == 0) ? nullptr : SKIPC;
      Key sub[4]; split_keys(cks[it], 4, sub);        // kv, kh0, kh1, ku
      UVec uv;
      for (int b = 0; b < NB; ++b) uv.u[b] = u01f(rbits(sub[3].a, sub[3].b, (u32)b, HALF_SMALL));
      if (!fixv) BERN(sub[0], SVP, sk);
      BERN(sub[1], SH0P, sk);
      BERN(sub[2], SH1P, sk);
      const float* f1;
      if (fixv) f1 = F[IV];
      else { GT(W0, SVP, b1, nullptr, F[IC], sk); f1 = F[IC]; }
      GT(W1, SH0P, b2, nullptr, F[ID], sk);
      ENERGY(fixv ? SV : SVP, SH0P, SH1P, f1, F[ID], E_PROP, sk);
      k_accept<<<dim3(32), dim3(64), 0, stream>>>(E_CUR, E_PROP, erun, CONV, ACC,
          fixv ? nullptr : PK[SVP], fixv ? nullptr : PK[SV],
          PK[SH0P], PK[SH0], PK[SH1P], PK[SH1], uv, it == 0 ? 1 : 0, sk);
      k_merge_xf<<<dim3(768), dim3(256), 0, stream>>>(ACC,
          (const u64*)XF[SH0P], (u64*)XF[SH0], (const u64*)XF[SH1P], (u64*)XF[SH1],
          fixv ? nullptr : (const u64*)XF[SVP], fixv ? nullptr : (u64*)XF[SV], sk);
      k_merge_pk<<<dim3(12), dim3(256), 0, stream>>>(ACC, PK[SH0P], PK[SH0], PK[SH1P], PK[SH1],
          fixv ? nullptr : PK[SVP], fixv ? nullptr : PK[SV], sk);
      k_allconv<<<dim3(1), dim3(1), 0, stream>>>(CONV, SKIPC);
    }
  };

  // ================= positive phase =================
  k_pos_v<<<dim3(96), dim3(256), 0, stream>>>(vin, XF[SV], PK[SV]);
  BERN(ks[0], SH0, nullptr);
  BERN(ks[1], SH1, nullptr);
  GT(W0, SV, b1, nullptr, F[IV], nullptr);            // fv = v@W0.T + b1 (constant in pos phase)
  u32 ev_ls_pos = mask32(ks[2]);
  ls_fixv(ev_ls_pos);
  u32 ev2_pos = mask32(ks[3]);
  Key g4[3]; split_keys(ks[4], 3, g4);                // kv(unused), kh0, kh1
  gibbs_fixv(ev2_pos, g4[1], g4[2]);
  GT(W1, SH0, b2, nullptr, F[ID], nullptr);           // f2 for energy(cur)
  ENERGY(SV, SH0, SH1, F[IV], F[ID], E_CUR, nullptr);
  coupling(true, ks[5], E_POS);

  // ================= negative phase =================
  BERN(ks[6], SV, nullptr);
  BERN(ks[7], SH0, nullptr);
  BERN(ks[8], SH1, nullptr);
  u32 ev_ls_neg = mask32(ks[9]);
  ls_free(ev_ls_neg);
  u32 ev2_neg = mask32(ks[10]);
  Key g11[3]; split_keys(ks[11], 3, g11);
  gibbs_free(ev2_neg, g11[0], g11[1], g11[2]);
  GT(W0, SV, b1, nullptr, F[IB], nullptr);            // f1 for energy(cur)
  GT(W1, SH0, b2, nullptr, F[IA], nullptr);           // f2
  ENERGY(SV, SH0, SH1, F[IB], F[IA], E_CUR, nullptr);
  coupling(false, ks[12], E_NEG);

  k_final<<<dim3(1), dim3(64), 0, stream>>>(E_POS, E_NEG, outp);
}

// Round 9
// 13495.067 us; speedup vs baseline: 1.1584x; 1.1584x over previous
//
#include <hip/hip_runtime.h>
#include <cstdint>
#include <math.h>

typedef unsigned int u32;
typedef unsigned long long u64;
typedef double d4 __attribute__((ext_vector_type(4)));

#define TF_PARTITIONABLE 1

#define NU 6144
#define NB 32
#define NTOT (NU * NB)      // 196608
#define NWORD 96            // u64 words per sample row
#define NCH 16              // split-K chunks per GEMM (grid 1536 = 6 blocks/CU)
#define CHK 384             // k per chunk (NCH*CHK = NU); 6 u64 words per row
#define NT_TILES 12         // CHK / 32
#define HALF_BIG 98304u
#define HALF_SMALL 16u

struct Key { u32 a, b; };
struct UVec { float u[NB]; };

// ---------------- threefry2x32 (20 rounds), matches jax._src.prng ----------------
__host__ __device__ __forceinline__ void tf2x32(u32 k0, u32 k1, u32 x0, u32 x1, u32& o0, u32& o1) {
  const u32 k2 = k0 ^ k1 ^ 0x1BD11BDAu;
#define TFR(r) { x0 += x1; x1 = (x1 << r) | (x1 >> (32 - r)); x1 ^= x0; }
  x0 += k0; x1 += k1;
  TFR(13) TFR(15) TFR(26) TFR(6)  x0 += k1; x1 += k2 + 1u;
  TFR(17) TFR(29) TFR(16) TFR(24) x0 += k2; x1 += k0 + 2u;
  TFR(13) TFR(15) TFR(26) TFR(6)  x0 += k0; x1 += k1 + 3u;
  TFR(17) TFR(29) TFR(16) TFR(24) x0 += k1; x1 += k2 + 4u;
  TFR(13) TFR(15) TFR(26) TFR(6)  x0 += k2; x1 += k0 + 5u;
#undef TFR
  o0 = x0; o1 = x1;
}

__host__ __device__ __forceinline__ u32 rbits(u32 k0, u32 k1, u32 t, u32 half) {
#if TF_PARTITIONABLE
  (void)half;
  u32 a, b; tf2x32(k0, k1, 0u, t, a, b); return a ^ b;
#else
  u32 a, b;
  if (t < half) { tf2x32(k0, k1, t, half + t, a, b); return a; }
  tf2x32(k0, k1, t - half, t, a, b); return b;
#endif
}

__host__ __device__ __forceinline__ float u01f(u32 bits) {
  union { u32 u; float f; } c; c.u = (bits >> 9) | 0x3f800000u;
  return c.f - 1.0f;
}

// ---------------- MFMA f64 layout self-calibration ----------------
__device__ __forceinline__ double pav(int probe, int l) {
  return probe ? (double)(((l * 13 + 5) & 63) + 1) : (double)(l + 1);
}
__device__ __forceinline__ double pbv(int probe, int l) {
  return probe ? (double)(((l * 11 + 2) & 63) + 1) : (double)(((l * 7 + 3) & 63) + 1);
}

// tbl[lane*16 + {0..8}] = mA,kA,nB,kB,bD0,bDs,jD0,jDs,ok
__global__ __launch_bounds__(64) void k_calib(int* __restrict__ tbl) {
  int L = threadIdx.x;
  d4 z = {0.0, 0.0, 0.0, 0.0};
  d4 o0 = __builtin_amdgcn_mfma_f64_16x16x4f64(pav(0, L), pbv(0, L), z, 0, 0, 0);
  d4 o1 = __builtin_amdgcn_mfma_f64_16x16x4f64(pav(1, L), pbv(1, L), z, 0, 0, 0);
  int q = L >> 4, m16 = L & 15;
  int best = -1;
  for (int combo = 0; combo < 16; ++combo) {
    int fa = combo & 1, fb = (combo >> 1) & 1, fd = combo >> 2;
    int ok = 1;
    for (int probe = 0; probe < 2; ++probe) {
#pragma unroll
      for (int r = 0; r < 4; ++r) {
        int i, j;
        if (fd == 0)      { j = m16; i = 4 * q + r; }
        else if (fd == 1) { j = m16; i = q + 4 * r; }
        else if (fd == 2) { i = m16; j = 4 * q + r; }
        else              { i = m16; j = q + 4 * r; }
        double pred = 0.0;
#pragma unroll
        for (int k = 0; k < 4; ++k) {
          int la = fa ? (i * 4 + k) : (k * 16 + i);
          int lb = fb ? (j * 4 + k) : (k * 16 + j);
          pred += pav(probe, la) * pbv(probe, lb);
        }
        double obs = probe ? (r == 0 ? o1[0] : r == 1 ? o1[1] : r == 2 ? o1[2] : o1[3])
                           : (r == 0 ? o0[0] : r == 1 ? o0[1] : r == 2 ? o0[2] : o0[3]);
        if (pred != obs) ok = 0;
      }
    }
    if (__all(ok) && best < 0) best = combo;
  }
  int mA = 0, kA = 0, nB = 0, kB = 0, b0_ = 0, bs = 0, j0 = 0, js = 0, okf = 0;
  if (best >= 0) {
    int fa = best & 1, fb = (best >> 1) & 1, fd = best >> 2;
    if (fa) { mA = L >> 2; kA = L & 3; } else { mA = m16; kA = q; }
    if (fb) { nB = L >> 2; kB = L & 3; } else { nB = m16; kB = q; }
    if (fd == 0)      { j0 = m16; js = 0; b0_ = 4 * q; bs = 1; }
    else if (fd == 1) { j0 = m16; js = 0; b0_ = q; bs = 4; }
    else if (fd == 2) { b0_ = m16; bs = 0; j0 = 4 * q; js = 1; }
    else              { b0_ = m16; bs = 0; j0 = q; js = 4; }
    okf = 1;
  }
  int* p = tbl + L * 16;
  p[0] = mA; p[1] = kA; p[2] = nB; p[3] = kB;
  p[4] = b0_; p[5] = bs; p[6] = j0; p[7] = js; p[8] = okf;
}

// ---------------- control kernels ----------------
__global__ void k_init(u32* __restrict__ flag, u32* __restrict__ chg) { *flag = 0u; *chg = 0u; }

__global__ void k_conv(u32* __restrict__ flag, u32* __restrict__ chg) {
  if (*flag == 0u && *chg == 0u) *flag = 1u;   // T=0 fixed point reached -> skip rest of LS
  *chg = 0u;
}

__global__ void k_allconv(const u32* __restrict__ conv, u32* __restrict__ skipc) {
  if (*skipc) return;
  u32 all = 1u;
  for (int b = 0; b < NB; ++b) all &= conv[b];
  if (all) *skipc = 1u;
}

// ---------------- state init (bit-packed only; states live in pk) ----------------
__global__ __launch_bounds__(256) void k_pos_v(const float* __restrict__ vin, u64* __restrict__ pk) {
  int tid = blockIdx.x * 256 + threadIdx.x;          // 24576 = 32*768
  int b = tid / 768, p = tid % 768;
  float x = vin[tid];
  int q = (int)floorf(x * 256.0f);
  q = q < 0 ? 0 : (q > 255 ? 255 : q);
  ((unsigned char*)pk)[b * 768 + p] = (unsigned char)q;   // byte == 8 LSB-first bits
}

__global__ __launch_bounds__(256) void k_bern(u32 k0, u32 k1, u64* __restrict__ pk) {
  int tid = blockIdx.x * 256 + threadIdx.x;          // 196608
  bool s = u01f(rbits(k0, k1, (u32)tid, HALF_BIG)) < 0.5f;
  u64 m = __ballot(s);
  if ((threadIdx.x & 63) == 0) pk[tid >> 6] = m;
}

// fused proposal generator for coupling (2 or 3 states, one dispatch)
__global__ __launch_bounds__(256) void k_bern3(u32 has_v, u32 va, u32 vb, u32 ha0, u32 hb0,
                                               u32 ha1, u32 hb1,
                                               u64* __restrict__ pkv, u64* __restrict__ pkh0,
                                               u64* __restrict__ pkh1, const u32* __restrict__ skip) {
  if (skip && *skip) return;
  int tid = blockIdx.x * 256 + threadIdx.x;
  int lane0 = (threadIdx.x & 63) == 0;
  if (has_v) {
    bool s = u01f(rbits(va, vb, (u32)tid, HALF_BIG)) < 0.5f;
    u64 m = __ballot(s);
    if (lane0) pkv[tid >> 6] = m;
  }
  { bool s = u01f(rbits(ha0, hb0, (u32)tid, HALF_BIG)) < 0.5f;
    u64 m = __ballot(s);
    if (lane0) pkh0[tid >> 6] = m; }
  { bool s = u01f(rbits(ha1, hb1, (u32)tid, HALF_BIG)) < 0.5f;
    u64 m = __ballot(s);
    if (lane0) pkh1[tid >> 6] = m; }
}

// ---------------- sampling ----------------
__device__ __forceinline__ bool samp_dec(float f, int t1, u32 k0, u32 k1, u32 tid) {
  if (t1) {
    double u = (double)u01f(rbits(k0, k1, tid, HALF_BIG));
    return u < 1.0 / (1.0 + exp(-(double)f));
  }
  return f >= 0.0f;
}

// merged sample over even mask (T=1 gibbs merges); writes pk only
__global__ __launch_bounds__(256) void k_samp(const float* __restrict__ fE, const float* __restrict__ fO,
                                              u32 even, int t1, u32 k0, u32 k1,
                                              u64* __restrict__ pk,
                                              const u32* __restrict__ skip, u32* __restrict__ chg) {
  if (skip && *skip) return;
  int tid = blockIdx.x * 256 + threadIdx.x;
  int b = tid / NU;
  float f = ((even >> b) & 1u) ? fE[tid] : fO[tid];
  bool s = samp_dec(f, t1, k0, k1, (u32)tid);
  u64 m = __ballot(s);
  if ((threadIdx.x & 63) == 0) {
    int widx = tid >> 6;
    if (chg) { u64 old = pk[widx]; if (old != m) *chg = 1u; }  // benign race
    pk[widx] = m;
  }
}

// ---------------- GEMM kernels: W LDS dbuf MFMA, x from packed bits; VALU fallback ----------------
// out[b][j] = sum_k x[k][b] * W[k][j]  (x @ W)
__global__ __launch_bounds__(256) void k_gemm_n(const float* __restrict__ W, const u64* __restrict__ pkx,
                                                double* __restrict__ part, const u32* __restrict__ skip,
                                                const int* __restrict__ tbl) {
  if (skip && *skip) return;
  __shared__ double smem_d[2560];              // 20480 B: W tiles [2][32][80] f32 / fallback red
  int jt = blockIdx.x % 96, c = blockIdx.x / 96;     // grid 96*NCH
  int wid = threadIdx.x >> 6, lane = threadIdx.x & 63;
  int kbase = c * CHK;
  int jn0 = jt * 64;
  const int* tp = tbl + lane * 16;
  int okf = tp[8];
  if (okf) {
    float* lw = (float*)smem_d;
    int mA = tp[0], kA = tp[1], nB = tp[2], kB = tp[3];
    int bD0 = tp[4], bDs = tp[5], jD0 = tp[6], jDs = tp[7];
    int t256 = threadIdx.x;
    d4 acc0 = {0.0, 0.0, 0.0, 0.0};
    d4 acc1 = {0.0, 0.0, 0.0, 0.0};
#pragma unroll
    for (int r = 0; r < 2; ++r) {
      int idx = r * 256 + t256, kk = idx >> 4, qq = idx & 15;
      float4 w4 = *(const float4*)(W + (size_t)(kbase + kk) * NU + jn0 + 4 * qq);
      float* d = &lw[kk * 80 + 4 * qq];
      d[0] = w4.x; d[1] = w4.y; d[2] = w4.z; d[3] = w4.w;
    }
    __syncthreads();
    const u64* pxr0 = pkx + (size_t)mA * NWORD + (kbase >> 6);
    const u64* pxr1 = pkx + (size_t)(mA + 16) * NWORD + (kbase >> 6);
    int buf = 0;
    for (int t = 0; t < NT_TILES; ++t) {
      float4 w0p, w1p;
      bool pf = (t + 1) < NT_TILES;
      if (pf) {
        int k0n = kbase + (t + 1) * 32;
        { int idx = t256,       kk = idx >> 4, qq = idx & 15;
          w0p = *(const float4*)(W + (size_t)(k0n + kk) * NU + jn0 + 4 * qq); }
        { int idx = 256 + t256, kk = idx >> 4, qq = idx & 15;
          w1p = *(const float4*)(W + (size_t)(k0n + kk) * NU + jn0 + 4 * qq); }
      }
      u64 ww0 = pxr0[t >> 1], ww1 = pxr1[t >> 1];
      u32 sh = ((u32)(t & 1) << 5) + (u32)kA;
      u32 bb0 = (u32)(ww0 >> sh), bb1 = (u32)(ww1 >> sh);
      const float* lwp = &lw[(buf * 32 + kB) * 80 + wid * 16 + nB];
#pragma unroll
      for (int u = 0; u < 8; ++u) {
        double a0 = (double)((bb0 >> (4 * u)) & 1u);
        double a1 = (double)((bb1 >> (4 * u)) & 1u);
        double wv = (double)lwp[320 * u];
        acc0 = __builtin_amdgcn_mfma_f64_16x16x4f64(a0, wv, acc0, 0, 0, 0);
        acc1 = __builtin_amdgcn_mfma_f64_16x16x4f64(a1, wv, acc1, 0, 0, 0);
      }
      if (pf) {
        int nb = buf ^ 1;
        { int idx = t256,       kk = idx >> 4, qq = idx & 15;
          float* d = &lw[(nb * 32 + kk) * 80 + 4 * qq];
          d[0] = w0p.x; d[1] = w0p.y; d[2] = w0p.z; d[3] = w0p.w; }
        { int idx = 256 + t256, kk = idx >> 4, qq = idx & 15;
          float* d = &lw[(nb * 32 + kk) * 80 + 4 * qq];
          d[0] = w1p.x; d[1] = w1p.y; d[2] = w1p.z; d[3] = w1p.w; }
      }
      __syncthreads();
      buf ^= 1;
    }
    int jn = jn0 + wid * 16;
    double* pp = part + (size_t)c * NTOT + jn;
#pragma unroll
    for (int r = 0; r < 4; ++r) {
      int bi = bD0 + bDs * r, jj = jD0 + jDs * r;
      pp[(size_t)bi * NU + jj] = acc0[r];
      pp[(size_t)(bi + 16) * NU + jj] = acc1[r];
    }
  } else {
    // VALU fallback (dead on this HW; correct-but-slow): wave wid sums k in [kbase+wid*96,+96)
    double* red = smem_d;
    int j = jn0 + lane;
    int i0 = kbase + wid * (CHK / 4);
    const float* wp = W + (size_t)i0 * NU + j;
    double acc[32];
#pragma unroll
    for (int b = 0; b < 32; ++b) acc[b] = 0.0;
    for (int i = 0; i < CHK / 4; ++i) {
      double w = (double)wp[(size_t)i * NU];
      int k = i0 + i;
#pragma unroll
      for (int b = 0; b < 32; ++b) {
        double xb = (double)((pkx[(size_t)b * NWORD + (k >> 6)] >> (k & 63)) & 1ull);
        acc[b] = fma(xb, w, acc[b]);
      }
    }
    for (int w = 1; w < 4; ++w) {
      if (wid == w) {
#pragma unroll
        for (int b = 0; b < 32; ++b) red[b * 64 + lane] = acc[b];
      }
      __syncthreads();
      if (wid == 0) {
#pragma unroll
        for (int b = 0; b < 32; ++b) acc[b] += red[b * 64 + lane];
      }
      __syncthreads();
    }
    if (wid == 0) {
      double* pp = part + (size_t)c * NTOT + j;
#pragma unroll
      for (int b = 0; b < 32; ++b) pp[(size_t)b * NU] = acc[b];
    }
  }
}

// out[b][j] = sum_k x[k][b] * W[j][k]  (x @ W.T); W staged natural [j][k], transposed at read
__global__ __launch_bounds__(256) void k_gemm_t(const float* __restrict__ W, const u64* __restrict__ pkx,
                                                double* __restrict__ part, const u32* __restrict__ skip,
                                                const int* __restrict__ tbl) {
  if (skip && *skip) return;
  __shared__ double smem_d[2176];              // 17408 B: W tiles [2][64][34] f32 / fallback
  int jt = blockIdx.x % 96, c = blockIdx.x / 96;
  int wid = threadIdx.x >> 6, lane = threadIdx.x & 63;
  int kbase = c * CHK;
  int jn0 = jt * 64;
  const int* tp = tbl + lane * 16;
  int okf = tp[8];
  if (okf) {
    float* lw = (float*)smem_d;
    int mA = tp[0], kA = tp[1], nB = tp[2], kB = tp[3];
    int bD0 = tp[4], bDs = tp[5], jD0 = tp[6], jDs = tp[7];
    int t256 = threadIdx.x;
    d4 acc0 = {0.0, 0.0, 0.0, 0.0};
    d4 acc1 = {0.0, 0.0, 0.0, 0.0};
#pragma unroll
    for (int r = 0; r < 2; ++r) {
      int idx = r * 256 + t256, jj = idx >> 3, kq = idx & 7;
      float4 w4 = *(const float4*)(W + (size_t)(jn0 + jj) * NU + kbase + 4 * kq);
      float* d = &lw[jj * 34 + 4 * kq];
      d[0] = w4.x; d[1] = w4.y; d[2] = w4.z; d[3] = w4.w;
    }
    __syncthreads();
    const u64* pxr0 = pkx + (size_t)mA * NWORD + (kbase >> 6);
    const u64* pxr1 = pkx + (size_t)(mA + 16) * NWORD + (kbase >> 6);
    int buf = 0;
    for (int t = 0; t < NT_TILES; ++t) {
      float4 w0p, w1p;
      bool pf = (t + 1) < NT_TILES;
      if (pf) {
        int k0n = kbase + (t + 1) * 32;
        { int idx = t256,       jj = idx >> 3, kq = idx & 7;
          w0p = *(const float4*)(W + (size_t)(jn0 + jj) * NU + k0n + 4 * kq); }
        { int idx = 256 + t256, jj = idx >> 3, kq = idx & 7;
          w1p = *(const float4*)(W + (size_t)(jn0 + jj) * NU + k0n + 4 * kq); }
      }
      u64 ww0 = pxr0[t >> 1], ww1 = pxr1[t >> 1];
      u32 sh = ((u32)(t & 1) << 5) + (u32)kA;
      u32 bb0 = (u32)(ww0 >> sh), bb1 = (u32)(ww1 >> sh);
      const float* lwp = &lw[(buf * 64 + wid * 16 + nB) * 34 + kB];
#pragma unroll
      for (int u = 0; u < 8; ++u) {
        double a0 = (double)((bb0 >> (4 * u)) & 1u);
        double a1 = (double)((bb1 >> (4 * u)) & 1u);
        double wv = (double)lwp[4 * u];
        acc0 = __builtin_amdgcn_mfma_f64_16x16x4f64(a0, wv, acc0, 0, 0, 0);
        acc1 = __builtin_amdgcn_mfma_f64_16x16x4f64(a1, wv, acc1, 0, 0, 0);
      }
      if (pf) {
        int nb = buf ^ 1;
        { int idx = t256,       jj = idx >> 3, kq = idx & 7;
          float* d = &lw[(nb * 64 + jj) * 34 + 4 * kq];
          d[0] = w0p.x; d[1] = w0p.y; d[2] = w0p.z; d[3] = w0p.w; }
        { int idx = 256 + t256, jj = idx >> 3, kq = idx & 7;
          float* d = &lw[(nb * 64 + jj) * 34 + 4 * kq];
          d[0] = w1p.x; d[1] = w1p.y; d[2] = w1p.z; d[3] = w1p.w; }
      }
      __syncthreads();
      buf ^= 1;
    }
    int jn = jn0 + wid * 16;
    double* pp = part + (size_t)c * NTOT + jn;
#pragma unroll
    for (int r = 0; r < 4; ++r) {
      int bi = bD0 + bDs * r, jj = jD0 + jDs * r;
      pp[(size_t)bi * NU + jj] = acc0[r];
      pp[(size_t)(bi + 16) * NU + jj] = acc1[r];
    }
  } else {
    // VALU fallback (dead): LDS-transposed W tiles; x from bits
    float* lwf = (float*)smem_d;               // 32x65 f32
    double* red = smem_d;                      // used strictly after last lwf read
    int qf = threadIdx.x & 7, af = threadIdx.x >> 3;
    double acc[32];
#pragma unroll
    for (int b = 0; b < 32; ++b) acc[b] = 0.0;
    for (int s = 0; s < NT_TILES; ++s) {
      int ib = kbase + s * 32;
#pragma unroll
      for (int pass = 0; pass < 2; ++pass) {
        int r = pass * 32 + af;
        float4 w4 = *(const float4*)(W + (size_t)(jn0 + r) * NU + ib + qf * 4);
        lwf[(qf * 4 + 0) * 65 + r] = w4.x;
        lwf[(qf * 4 + 1) * 65 + r] = w4.y;
        lwf[(qf * 4 + 2) * 65 + r] = w4.z;
        lwf[(qf * 4 + 3) * 65 + r] = w4.w;
      }
      __syncthreads();
      int iw = wid * 8;
      for (int ii = 0; ii < 8; ++ii) {
        double w = (double)lwf[(iw + ii) * 65 + lane];
        int k = ib + iw + ii;
#pragma unroll
        for (int b = 0; b < 32; ++b) {
          double xb = (double)((pkx[(size_t)b * NWORD + (k >> 6)] >> (k & 63)) & 1ull);
          acc[b] = fma(xb, w, acc[b]);
        }
      }
      __syncthreads();
    }
    for (int w = 1; w < 4; ++w) {
      if (wid == w) {
#pragma unroll
        for (int b = 0; b < 32; ++b) red[b * 64 + lane] = acc[b];
      }
      __syncthreads();
      if (wid == 0) {
#pragma unroll
        for (int b = 0; b < 32; ++b) acc[b] += red[b * 64 + lane];
      }
      __syncthreads();
    }
    if (wid == 0) {
      double* pp = part + (size_t)c * NTOT + jn0 + lane;
#pragma unroll
      for (int b = 0; b < 32; ++b) pp[(size_t)b * NU] = acc[b];
    }
  }
}

// ---------------- reduce (+ optional fused sample) ----------------
__global__ __launch_bounds__(256) void k_reduce(const double* __restrict__ part, const float* __restrict__ bias,
                                                const float* __restrict__ src, float* __restrict__ out,
                                                const u32* __restrict__ skip) {
  if (skip && *skip) return;
  int tid = blockIdx.x * 256 + threadIdx.x;
  int j = tid % NU;
  double s = src ? (double)src[tid] : 0.0;
  if (bias) s += (double)bias[j];
#pragma unroll
  for (int c = 0; c < NCH; ++c) s += part[(size_t)c * NTOT + tid];
  out[tid] = (float)s;
}

// reduce -> (optional out); sample into pk for batch rows in wmask; optional chg detection
__global__ __launch_bounds__(256) void k_redsamp(const double* __restrict__ part, const float* __restrict__ bias,
                                                 const float* __restrict__ src, float* __restrict__ out,
                                                 int t1, u32 k0, u32 k1,
                                                 u64* __restrict__ pk,
                                                 const u32* __restrict__ skip, u32 wmask,
                                                 u32* __restrict__ chg) {
  if (skip && *skip) return;
  int tid = blockIdx.x * 256 + threadIdx.x;
  int j = tid % NU, b = tid / NU;
  double s = src ? (double)src[tid] : 0.0;
  if (bias) s += (double)bias[j];
#pragma unroll
  for (int c = 0; c < NCH; ++c) s += part[(size_t)c * NTOT + tid];
  float f = (float)s;
  if (out) out[tid] = f;
  bool wr = (wmask >> b) & 1u;
  bool smp = samp_dec(f, t1, k0, k1, (u32)tid);
  u64 m = __ballot(smp);
  if (((threadIdx.x & 63) == 0) && wr) {
    int widx = tid >> 6;
    if (chg) { u64 old = pk[widx]; if (old != m) *chg = 1u; }
    pk[widx] = m;
  }
  (void)j;
}

// ---------------- energy / accept / merge ----------------
__global__ __launch_bounds__(256) void k_energy(const u64* __restrict__ pkv, const u64* __restrict__ pkh0,
                                                const u64* __restrict__ pkh1, const float* __restrict__ f1,
                                                const float* __restrict__ f2, const float* __restrict__ b0,
                                                float* __restrict__ eout, const u32* __restrict__ skip) {
  if (skip && *skip) return;
  __shared__ double red[256];
  int b = blockIdx.x, t = threadIdx.x;
  double s = 0.0;
  for (int j = t; j < NU; j += 256) {
    int w = j >> 6, bit = j & 63;
    if ((pkv [b * NWORD + w] >> bit) & 1ull) s += (double)b0[j];
    if ((pkh0[b * NWORD + w] >> bit) & 1ull) s += (double)f1[(size_t)b * NU + j];
    if ((pkh1[b * NWORD + w] >> bit) & 1ull) s += (double)f2[(size_t)b * NU + j];
  }
  red[t] = s; __syncthreads();
  for (int off = 128; off > 0; off >>= 1) { if (t < off) red[t] += red[t + off]; __syncthreads(); }
  if (t == 0) eout[b] = (float)(-red[0]);
}

__global__ __launch_bounds__(64) void k_accept(float* __restrict__ ecur, const float* __restrict__ eprop,
                                               float* __restrict__ erun, u32* __restrict__ conv,
                                               u32* __restrict__ accf,
                                               const u64* __restrict__ pv, const u64* __restrict__ pcv,
                                               const u64* __restrict__ ph0, const u64* __restrict__ pch0,
                                               const u64* __restrict__ ph1, const u64* __restrict__ pch1,
                                               UVec uv, int first, const u32* __restrict__ skip) {
  if (skip && *skip) return;
  int b = blockIdx.x, t = threadIdx.x;
  u64 diff = 0ull;
  for (int w = t; w < NWORD; w += 64) {
    size_t o = (size_t)b * NWORD + w;
    if (pv) diff |= pv[o] ^ pcv[o];
    diff |= ph0[o] ^ pch0[o];
    diff |= ph1[o] ^ pch1[o];
  }
  int neq = __any(diff != 0ull);
  if (t == 0) {
    float ec = ecur[b], ep = eprop[b];
    bool acc = (double)uv.u[b] < exp(fmin((double)ec - (double)ep, 0.0));
    bool m = first ? true : (conv[b] == 0u);
    bool upd = m && acc;
    if (first) erun[b] = acc ? ep : ec;
    else if (upd) erun[b] += (ep - ec);
    if (upd) ecur[b] = ep;
    u32 c2 = acc ? (neq ? 0u : 1u) : 1u;
    conv[b] = first ? c2 : (conv[b] | c2);
    accf[b] = upd ? 1u : 0u;
  }
}

__global__ __launch_bounds__(256) void k_merge_pk(const u32* __restrict__ accf,
                                                  const u64* __restrict__ pa, u64* __restrict__ ca,
                                                  const u64* __restrict__ pb, u64* __restrict__ cb,
                                                  const u64* __restrict__ pc, u64* __restrict__ cc,
                                                  const u32* __restrict__ skip) {
  if (skip && *skip) return;
  int w = blockIdx.x * 256 + threadIdx.x;
  if (w >= NB * NWORD) return;
  int b = w / NWORD;
  if (accf[b]) {
    ca[w] = pa[w];
    cb[w] = pb[w];
    if (pc) cc[w] = pc[w];
  }
}

__global__ void k_final(const float* __restrict__ ep, const float* __restrict__ en, float* __restrict__ out) {
  int b = threadIdx.x;
  if (b < NB) out[b] = ep[b] - en[b];
}

// ---------------- host-side key derivation ----------------
static void split_keys(Key k, int n, Key* out) {
#if TF_PARTITIONABLE
  for (int i = 0; i < n; ++i) { u32 a, b; tf2x32(k.a, k.b, 0u, (u32)i, a, b); out[i].a = a; out[i].b = b; }
#else
  u32 flat[64];
  for (int i = 0; i < n; ++i) { u32 a, b; tf2x32(k.a, k.b, (u32)i, (u32)(n + i), a, b); flat[i] = a; flat[n + i] = b; }
  for (int i = 0; i < n; ++i) { out[i].a = flat[2 * i]; out[i].b = flat[2 * i + 1]; }
#endif
}
static u32 mask32(Key k) {
  u32 m = 0;
  for (int b = 0; b < NB; ++b)
    if (u01f(rbits(k.a, k.b, (u32)b, HALF_SMALL)) < 0.5f) m |= (1u << b);
  return m;
}

extern "C" void kernel_launch(void* const* d_in, const int* in_sizes, int n_in,
                              void* d_out, int out_size, void* d_ws, size_t ws_size,
                              hipStream_t stream) {
  const float* vin = (const float*)d_in[0];
  const float* W0  = (const float*)d_in[1];
  const float* W1  = (const float*)d_in[2];
  const float* b0  = (const float*)d_in[3];
  const float* b1  = (const float*)d_in[4];
  const float* b2  = (const float*)d_in[5];
  float* outp = (float*)d_out;

  // ---- workspace layout (~31 MB) ----
  char* ws = (char*)d_ws;
  size_t off = 0;
  auto alloc = [&](size_t bytes) -> void* {
    void* p = ws + off; off += (bytes + 255) & ~(size_t)255; return p;
  };
  enum { SV = 0, SH0, SH1, SVE, SH1E, SH0O, SVP, SH0P, SH1P, NS };
  enum { IV = 0, IA, IB, IC, ID, IE, IF2, NF };
  u64* PK[NS]; float* F[NF];
  for (int f = 0; f < NF; ++f) F[f] = (float*)alloc((size_t)NTOT * 4);
  double* PART = (double*)alloc((size_t)NCH * NTOT * 8);
  for (int s = 0; s < NS; ++s) PK[s] = (u64*)alloc((size_t)NB * NWORD * 8);
  int*   TBL    = (int*)alloc(64 * 16 * 4);
  float* E_CUR  = (float*)alloc(256);
  float* E_PROP = (float*)alloc(256);
  float* E_POS  = (float*)alloc(256);
  float* E_NEG  = (float*)alloc(256);
  u32*   ACC    = (u32*)alloc(256);
  u32*   CONV   = (u32*)alloc(256);
  u32*   FLAG   = (u32*)alloc(256);
  u32*   CHG    = (u32*)alloc(256);
  u32*   SKIPC  = (u32*)alloc(256);
  u32*   DUMMY  = (u32*)alloc(256);
  if (off > ws_size) return;

  // ---- host RNG: full key tree from jax.random.key(42) ----
  Key root{0u, 42u};
  Key ks[13]; split_keys(root, 13, ks);
  const Key KZ{0u, 0u};

  // ---- MFMA layout calibration (deterministic, graph-safe) ----
  k_calib<<<dim3(1), dim3(64), 0, stream>>>(TBL);

  // ---- launch helpers ----
  auto GEMM_T = [&](const float* Wm, int xs, const u32* skip) {
    k_gemm_t<<<dim3(96 * NCH), dim3(256), 0, stream>>>(Wm, PK[xs], PART, skip, TBL);
  };
  auto GEMM_N = [&](const float* Wm, int xs, const u32* skip) {
    k_gemm_n<<<dim3(96 * NCH), dim3(256), 0, stream>>>(Wm, PK[xs], PART, skip, TBL);
  };
  auto RED = [&](const float* bias, const float* src, float* dst, const u32* skip) {
    k_reduce<<<dim3(768), dim3(256), 0, stream>>>(PART, bias, src, dst, skip);
  };
  auto REDS = [&](const float* bias, const float* src, float* dst, int t1, Key k, int sdst,
                  const u32* skip, u32 wm, u32* chg) {
    k_redsamp<<<dim3(768), dim3(256), 0, stream>>>(PART, bias, src, dst, t1, k.a, k.b,
                                                   PK[sdst], skip, wm, chg);
  };
  auto GT = [&](const float* Wm, int xs, const float* bias, const float* src, float* dst, const u32* skip) {
    GEMM_T(Wm, xs, skip); RED(bias, src, dst, skip);
  };
  auto GN = [&](const float* Wm, int xs, const float* bias, const float* src, float* dst, const u32* skip) {
    GEMM_N(Wm, xs, skip); RED(bias, src, dst, skip);
  };
  auto GTS = [&](const float* Wm, int xs, const float* bias, const float* src, float* dst,
                 int t1, Key k, int sdst, const u32* skip) {
    GEMM_T(Wm, xs, skip); REDS(bias, src, dst, t1, k, sdst, skip, ~0u, nullptr);
  };
  auto GNS = [&](const float* Wm, int xs, const float* bias, const float* src, float* dst,
                 int t1, Key k, int sdst, const u32* skip) {
    GEMM_N(Wm, xs, skip); REDS(bias, src, dst, t1, k, sdst, skip, ~0u, nullptr);
  };
  auto SAMP = [&](const float* fE, const float* fO, u32 even, int t1, Key k, int dst,
                  const u32* skip, u32* chg) {
    k_samp<<<dim3(768), dim3(256), 0, stream>>>(fE, fO, even, t1, k.a, k.b, PK[dst], skip, chg);
  };
  auto BERN = [&](Key k, int dst) {
    k_bern<<<dim3(768), dim3(256), 0, stream>>>(k.a, k.b, PK[dst]);
  };
  auto ENERGY = [&](int sv, int sh0, int sh1, const float* f1, const float* f2, float* eo, const u32* skip) {
    k_energy<<<dim3(32), dim3(256), 0, stream>>>(PK[sv], PK[sh0], PK[sh1], f1, f2, b0, eo, skip);
  };

  // ===== staggered T=0 local search (round-7 proven; bits-only states) =====
  auto ls_fixv = [&](u32 evm) {
    auto X = [&](u32 wm) {
      GEMM_T(W1, SH0, FLAG);
      REDS(b2, nullptr, nullptr, 0, KZ, SH1, FLAG, wm, CHG);
    };
    auto Y = [&]() {
      GEMM_N(W1, SH1, FLAG);
      REDS(nullptr, F[IV], nullptr, 0, KZ, SH0, FLAG, ~0u, CHG);
    };
    k_init<<<dim3(1), dim3(1), 0, stream>>>(FLAG, CHG);
    X(evm);
    for (int i = 0; i < 31; ++i) {
      Y(); X(~0u);
      k_conv<<<dim3(1), dim3(1), 0, stream>>>(FLAG, CHG);
    }
    Y(); X(~evm);
  };
  auto ls_free = [&](u32 evm) {
    auto X = [&](u32 wm) {
      GEMM_N(W0, SH0, FLAG);
      REDS(b0, nullptr, nullptr, 0, KZ, SV, FLAG, wm, CHG);
      GEMM_T(W1, SH0, FLAG);
      REDS(b2, nullptr, nullptr, 0, KZ, SH1, FLAG, wm, CHG);
    };
    auto Y = [&]() {
      GT(W0, SV, b1, nullptr, F[IC], FLAG);
      GEMM_N(W1, SH1, FLAG);
      REDS(nullptr, F[IC], nullptr, 0, KZ, SH0, FLAG, ~0u, CHG);
    };
    k_init<<<dim3(1), dim3(1), 0, stream>>>(FLAG, CHG);
    X(evm);
    for (int i = 0; i < 31; ++i) {
      Y(); X(~0u);
      k_conv<<<dim3(1), dim3(1), 0, stream>>>(FLAG, CHG);
    }
    Y(); X(~evm);
  };

  // ===== T=1 gibbs steps =====
  auto gibbs_fixv = [&](u32 even, Key kh0, Key kh1) {
    GTS(W1, SH0, b2, nullptr, F[IA], 1, kh1, SH1E, nullptr);     // f_h1e ; h1_e
    GN(W1, SH1E, nullptr, F[IV], F[IB], nullptr);                // f_h0e = fv + h1_e@W1
    GNS(W1, SH1, nullptr, F[IV], F[IC], 1, kh0, SH0O, nullptr);  // f_h0o ; h0_o
    GT(W1, SH0O, b2, nullptr, F[ID], nullptr);                   // f_h1o
    SAMP(F[IB], F[IC], even, 1, kh0, SH0, nullptr, nullptr);     // h0 merge
    SAMP(F[IA], F[ID], even, 1, kh1, SH1, nullptr, nullptr);     // h1 merge
  };
  auto gibbs_free = [&](u32 even, Key kv, Key kh0, Key kh1) {
    GNS(W0, SH0, b0, nullptr, F[IE], 1, kv, SVE, nullptr);       // f_ve ; v_e
    GTS(W1, SH0, b2, nullptr, F[IA], 1, kh1, SH1E, nullptr);     // f_h1e ; h1_e
    GT(W0, SVE, b1, nullptr, F[IB], nullptr);                    // f_h0e = v_e@W0.T + b1
    GN(W1, SH1E, nullptr, F[IB], F[IB], nullptr);                //        + h1_e@W1
    GT(W0, SV, b1, nullptr, F[IC], nullptr);                     // f_h0o = v@W0.T + b1
    GNS(W1, SH1, nullptr, F[IC], F[IC], 1, kh0, SH0O, nullptr);  //        + h1@W1 ; h0_o
    GN(W0, SH0O, b0, nullptr, F[IF2], nullptr);                  // f_vo
    GT(W1, SH0O, b2, nullptr, F[ID], nullptr);                   // f_h1o
    SAMP(F[IE], F[IF2], even, 1, kv, SV, nullptr, nullptr);      // v merge
    SAMP(F[IB], F[IC], even, 1, kh0, SH0, nullptr, nullptr);     // h0 merge
    SAMP(F[IA], F[ID], even, 1, kh1, SH1, nullptr, nullptr);     // h1 merge
  };

  // ===== coupling; E_CUR holds energy(cur); fixv uses F[IV]=fv; all-conv skips rest =====
  auto coupling = [&](bool fixv, Key ck, float* erun) {
    Key top[2]; split_keys(ck, 2, top);
    Key cks[17]; cks[0] = top[0];
    { Key rest[16]; split_keys(top[1], 16, rest); for (int i = 0; i < 16; ++i) cks[i + 1] = rest[i]; }
    k_init<<<dim3(1), dim3(1), 0, stream>>>(SKIPC, DUMMY);
    for (int it = 0; it < 17; ++it) {
      const u32* sk = (it == 0) ? nullptr : SKIPC;
      Key sub[4]; split_keys(cks[it], 4, sub);        // kv, kh0, kh1, ku
      UVec uv;
      for (int b = 0; b < NB; ++b) uv.u[b] = u01f(rbits(sub[3].a, sub[3].b, (u32)b, HALF_SMALL));
      k_bern3<<<dim3(768), dim3(256), 0, stream>>>(fixv ? 0u : 1u,
          sub[0].a, sub[0].b, sub[1].a, sub[1].b, sub[2].a, sub[2].b,
          PK[SVP], PK[SH0P], PK[SH1P], sk);
      const float* f1;
      if (fixv) f1 = F[IV];
      else { GT(W0, SVP, b1, nullptr, F[IC], sk); f1 = F[IC]; }
      GT(W1, SH0P, b2, nullptr, F[ID], sk);
      ENERGY(fixv ? SV : SVP, SH0P, SH1P, f1, F[ID], E_PROP, sk);
      k_accept<<<dim3(32), dim3(64), 0, stream>>>(E_CUR, E_PROP, erun, CONV, ACC,
          fixv ? nullptr : PK[SVP], fixv ? nullptr : PK[SV],
          PK[SH0P], PK[SH0], PK[SH1P], PK[SH1], uv, it == 0 ? 1 : 0, sk);
      k_merge_pk<<<dim3(12), dim3(256), 0, stream>>>(ACC, PK[SH0P], PK[SH0], PK[SH1P], PK[SH1],
          fixv ? nullptr : PK[SVP], fixv ? nullptr : PK[SV], sk);
      k_allconv<<<dim3(1), dim3(1), 0, stream>>>(CONV, SKIPC);
    }
  };

  // ================= positive phase =================
  k_pos_v<<<dim3(96), dim3(256), 0, stream>>>(vin, PK[SV]);
  BERN(ks[0], SH0);
  BERN(ks[1], SH1);
  GT(W0, SV, b1, nullptr, F[IV], nullptr);            // fv = v@W0.T + b1 (constant in pos phase)
  u32 ev_ls_pos = mask32(ks[2]);
  ls_fixv(ev_ls_pos);
  u32 ev2_pos = mask32(ks[3]);
  Key g4[3]; split_keys(ks[4], 3, g4);                // kv(unused), kh0, kh1
  gibbs_fixv(ev2_pos, g4[1], g4[2]);
  GT(W1, SH0, b2, nullptr, F[ID], nullptr);           // f2 for energy(cur)
  ENERGY(SV, SH0, SH1, F[IV], F[ID], E_CUR, nullptr);
  coupling(true, ks[5], E_POS);

  // ================= negative phase =================
  BERN(ks[6], SV);
  BERN(ks[7], SH0);
  BERN(ks[8], SH1);
  u32 ev_ls_neg = mask32(ks[9]);
  ls_free(ev_ls_neg);
  u32 ev2_neg = mask32(ks[10]);
  Key g11[3]; split_keys(ks[11], 3, g11);
  gibbs_free(ev2_neg, g11[0], g11[1], g11[2]);
  GT(W0, SV, b1, nullptr, F[IB], nullptr);            // f1 for energy(cur)
  GT(W1, SH0, b2, nullptr, F[IA], nullptr);           // f2
  ENERGY(SV, SH0, SH1, F[IB], F[IA], E_CUR, nullptr);
  coupling(false, ks[12], E_NEG);

  k_final<<<dim3(1), dim3(64), 0, stream>>>(E_POS, E_NEG, outp);
}